// Round 4
// baseline (314.934 us; speedup 1.0000x reference)
//
#include <hip/hip_runtime.h>
#include <hip/hip_bf16.h>

// LocallyConnected2d: y[b,o,h,w] = bias[o,h,w] +
//   sum_{i,kh,kw} xpad[b,i,h+kh,w+kw] * weight[i,o,h,w,kh,kw]
// B=64, CIN=COUT=64, H=W=32, K=3, pad=1, fp32 in/out.
// Per-loc GEMM Y[64b][64o] += X[64b][576k] W[576k][64o] on bf16 MFMA.
// Round 4: pre-format BOTH operands into MFMA fragment order (af = A-frags,
// wt2 = B-frags). Main GEMM is LDS-free and barrier-free: pure dwordx4
// streaming + MFMA with depth-1 prefetch.

#define B_    64
#define HW_   32
#define HP_   34
#define NLOC  1024
#define W_OST 9216u     // floats per o step
#define W_IST 589824u   // floats per i step
#define XT_BYTES  ((size_t)64*HP_*HP_*64*2)          //  9,469,952
#define WT2_BYTES ((size_t)NLOC*18*4*64*16)          // 75,497,472
#define AF_BYTES  ((size_t)NLOC*18*4*64*16)          // 75,497,472
#define WS_NEED   (XT_BYTES + WT2_BYTES + AF_BYTES)  // 160,464,896

typedef __attribute__((ext_vector_type(8))) short short8;
typedef __attribute__((ext_vector_type(8))) unsigned short ushort8;
typedef __attribute__((ext_vector_type(4))) float floatx4;

static __device__ __forceinline__ unsigned short f2bf(float f) {
  __hip_bfloat16 h = __float2bfloat16(f);   // RNE
  return __builtin_bit_cast(unsigned short, h);
}

// ---------------------------------------------------------------------------
// Kernel 1: pad+transpose x[b][i][h][w] (fp32) -> xt[i][hh][ww][b] (bf16).
// (verified rounds 2-3)
// ---------------------------------------------------------------------------
__global__ __launch_bounds__(256) void xpose_pad(const float* __restrict__ x,
                                                 unsigned short* __restrict__ xt) {
  int bid = blockIdx.x;                 // 64*34
  int i = bid / HP_, hh = bid % HP_;
  __shared__ float tile[B_ * 33];
  int t = threadIdx.x;
  bool interior = (hh >= 1 && hh <= HW_);
  if (interior) {
    int h = hh - 1, w = t & 31, bs = t >> 5;
    #pragma unroll
    for (int r = 0; r < 8; ++r) {
      int b = r * 8 + bs;
      tile[b * 33 + w] = x[(((size_t)b * 64 + i) * HW_ + h) * HW_ + w];
    }
  }
  __syncthreads();
  int b = t & 63, wsb = t >> 6;
  size_t base = (size_t)(i * HP_ + hh) * HP_ * B_;
  #pragma unroll
  for (int s = 0; s < 9; ++s) {
    int ww = s * 4 + wsb;
    if (ww < HP_) {
      float v = 0.f;
      if (interior && ww >= 1 && ww <= HW_) v = tile[b * 33 + (ww - 1)];
      xt[base + (size_t)ww * B_ + b] = f2bf(v);
    }
  }
}

// ---------------------------------------------------------------------------
// Kernel 2: im2col in MFMA A-fragment order.
// af[((loc*18+c)*4+tl)*64+l][j] = x[b=tl*16+(l&15)][k=c*32+(l>>4)*8+j]
// Same verified per-wave 2-step LDS transpose as rounds 2-3, destination
// global instead of LDS. No __syncthreads needed (scr is per-wave).
// ---------------------------------------------------------------------------
__global__ __launch_bounds__(256) void im2col_frag(
    const unsigned short* __restrict__ xt,
    unsigned short* __restrict__ af) {
  __shared__ unsigned short scr[4][512];
  const int bid  = blockIdx.x;
  const int loc  = ((bid & 7) << 7) | (bid >> 3);   // XCD swizzle
  const int hblk = loc >> 5, wblk = loc & 31;
  const int tid  = threadIdx.x;
  const int lane = tid & 63;
  const int wv   = tid >> 6;

  #pragma unroll 2
  for (int c = 0; c < 18; ++c) {
    // step 1: coalesced load of 8 k-rows x 64 b (1 KB) into wave scratch
    int k  = c * 32 + wv * 8 + (lane >> 3);
    int i  = k / 9, q = k - i * 9;
    int kh = q / 3, kw = q - kh * 3;
    const ushort8* src = (const ushort8*)(xt +
        (((unsigned)i * HP_ + (unsigned)(hblk + kh)) * HP_ + (unsigned)(wblk + kw)) * 64u
        + ((unsigned)(lane & 7) << 3));
    ushort8 v = *src;
    *(ushort8*)&scr[wv][lane << 3] = v;
    __asm__ volatile("s_waitcnt lgkmcnt(0)" ::: "memory");
    // step 2: lane-transpose: lane packs b=lane's 8 j-values -> one frag slot
    ushort8 p;
    #pragma unroll
    for (int jr = 0; jr < 8; ++jr) p[jr] = scr[wv][jr * 64 + lane];
    __asm__ volatile("s_waitcnt lgkmcnt(0)" ::: "memory");  // reads done before next overwrite
    size_t slot = ((size_t)(loc * 18 + c) * 4 + (size_t)(lane >> 4)) * 64
                + (size_t)((lane & 15) + (wv << 4));
    *(ushort8*)(af + (slot << 3)) = p;
  }
}

// ---------------------------------------------------------------------------
// Kernel 3: weight -> wt2 in MFMA B-fragment order, bf16. (verified round 3)
// ---------------------------------------------------------------------------
__global__ __launch_bounds__(256) void wtrans(const float* __restrict__ wsrc,
                                              unsigned short* __restrict__ wt2) {
  __shared__ unsigned short lds[16 * 2 * 584];   // [o16][loc2][k576 pad->584]
  int bid  = blockIdx.x;                         // 4 * 512
  int tile = bid & 3;
  int lblk = bid >> 2;
  int o0 = tile * 16, loc0 = lblk * 2;
  int t = threadIdx.x;

  #pragma unroll 4
  for (int s = 0; s < 36; ++s) {
    int f = (s * 256 + t) * 2;
    int i = f / 288;
    int rem = f - i * 288;
    int o = rem / 18;
    int q = rem - o * 18;                        // 0..17, even
    const float2 v = *(const float2*)(wsrc + (size_t)i * W_IST
                                      + (size_t)(o0 + o) * W_OST
                                      + (size_t)loc0 * 9 + q);
    int lc0 = q / 9, kk0 = q - lc0 * 9;
    lds[(o * 2 + lc0) * 584 + i * 9 + kk0] = f2bf(v.x);
    int q1 = q + 1, lc1 = q1 / 9, kk1 = q1 - lc1 * 9;
    lds[(o * 2 + lc1) * 584 + i * 9 + kk1] = f2bf(v.y);
  }
  __syncthreads();

  int lane = t & 63, wv = t >> 6;
  int on = lane & 15, quad = lane >> 4;
  #pragma unroll
  for (int r = 0; r < 9; ++r) {
    int sid = wv * 9 + r;
    int lc = sid / 18, c = sid - lc * 18;
    int k0 = c * 32 + quad * 8;
    ushort8 v = *(const ushort8*)&lds[(on * 2 + lc) * 584 + k0];
    *(ushort8*)(wt2 + ((((size_t)(loc0 + lc) * 18 + c) * 4 + tile) * 64 + lane) * 8) = v;
  }
}

// ---------------------------------------------------------------------------
// Kernel 4: streaming GEMM. One block per loc, 4 waves = 4 o-tiles.
// No LDS, no barriers: A-frags and B-frags via direct dwordx4 in fragment
// order, depth-1 prefetch, 4 MFMA per chunk per wave.
// ---------------------------------------------------------------------------
__global__ __launch_bounds__(256, 4) void lc2d_stream(
    const unsigned short* __restrict__ af,
    const unsigned short* __restrict__ wt2,
    const float* __restrict__ bias,
    float* __restrict__ out) {
  const int bid  = blockIdx.x;
  const int loc  = ((bid & 7) << 7) | (bid >> 3);   // XCD swizzle
  const int tid  = threadIdx.x;
  const int lane = tid & 63;
  const int wv   = tid >> 6;
  const int h4   = lane >> 4;
  const int oo   = (wv << 4) + (lane & 15);

  floatx4 acc[4];
  {
    float bv = bias[(unsigned)oo * 1024u + (unsigned)loc];
    floatx4 z = {bv, bv, bv, bv};
    acc[0] = z; acc[1] = z; acc[2] = z; acc[3] = z;
  }

  const size_t abase = ((size_t)loc * 18) * 4 * 64 * 8 + ((size_t)lane << 3);
  const size_t bbase = ((size_t)loc * 18 * 4 + (size_t)wv) * 64 * 8 + ((size_t)lane << 3);

  auto ldA = [&](int c, int tl) {
    return *(const ushort8*)(af + abase + ((size_t)(c * 4 + tl) << 9));
  };
  auto ldB = [&](int c) {
    return *(const ushort8*)(wt2 + bbase + ((size_t)c << 11));
  };

  ushort8 na0 = ldA(0, 0), na1 = ldA(0, 1), na2 = ldA(0, 2), na3 = ldA(0, 3);
  ushort8 nb  = ldB(0);

  #pragma unroll
  for (int c = 0; c < 18; ++c) {
    ushort8 a0 = na0, a1 = na1, a2 = na2, a3 = na3, b = nb;
    if (c + 1 < 18) {
      na0 = ldA(c + 1, 0); na1 = ldA(c + 1, 1);
      na2 = ldA(c + 1, 2); na3 = ldA(c + 1, 3);
      nb  = ldB(c + 1);
    }
    acc[0] = __builtin_amdgcn_mfma_f32_16x16x32_bf16(
        __builtin_bit_cast(short8, a0), __builtin_bit_cast(short8, b), acc[0], 0, 0, 0);
    acc[1] = __builtin_amdgcn_mfma_f32_16x16x32_bf16(
        __builtin_bit_cast(short8, a1), __builtin_bit_cast(short8, b), acc[1], 0, 0, 0);
    acc[2] = __builtin_amdgcn_mfma_f32_16x16x32_bf16(
        __builtin_bit_cast(short8, a2), __builtin_bit_cast(short8, b), acc[2], 0, 0, 0);
    acc[3] = __builtin_amdgcn_mfma_f32_16x16x32_bf16(
        __builtin_bit_cast(short8, a3), __builtin_bit_cast(short8, b), acc[3], 0, 0, 0);
  }

  // epilogue: D lane mapping col=o=lane&15, row=b=tile*16 + h4*4 + r (verified)
  #pragma unroll
  for (int tl = 0; tl < 4; ++tl) {
    int brow = tl * 16 + h4 * 4;
    #pragma unroll
    for (int r = 0; r < 4; ++r)
      out[((unsigned)(brow + r) * 64u + (unsigned)oo) * 1024u + (unsigned)loc] = acc[tl][r];
  }
}

// ---------------------------------------------------------------------------
// Fallback (tiny ws): fp32, direct x reads (round 1, correct for any ws).
// ---------------------------------------------------------------------------
__global__ __launch_bounds__(256, 4) void lc2d_fallback(
    const float* __restrict__ x, const float* __restrict__ weight,
    const float* __restrict__ bias, float* __restrict__ out) {
  int t0 = blockIdx.x;
  int loc = ((t0 & 7) << 7) | (t0 >> 3);
  int h = loc >> 5, w = loc & 31;
  int tid = threadIdx.x;
  int b = tid & 63;
  int o0 = (tid >> 6) * 16;
  __shared__ float As[72 * 64];
  float acc[16];
  #pragma unroll
  for (int j = 0; j < 16; ++j) acc[j] = bias[(size_t)(o0 + j) * NLOC + loc];
  for (int ic = 0; ic < 8; ++ic) {
    __syncthreads();
    #pragma unroll
    for (int s = 0; s < 18; ++s) {
      int f = s * 256 + tid;
      int k = f >> 6, lb = f & 63;
      int kk = k >> 3, isub = k & 7;
      int i = ic * 8 + isub;
      int kh = kk / 3, kw = kk - kh * 3;
      int hh = h + kh - 1, ww = w + kw - 1;
      float v = (hh >= 0 && hh < HW_ && ww >= 0 && ww < HW_)
                  ? x[(((size_t)lb * 64 + i) * HW_ + hh) * HW_ + ww] : 0.f;
      As[k * 64 + lb] = v;
    }
    __syncthreads();
    #pragma unroll 1
    for (int isub = 0; isub < 8; ++isub) {
      const float* wp = weight + (size_t)(ic * 8 + isub) * W_IST
                               + (size_t)o0 * W_OST + loc * 9;
      #pragma unroll
      for (int kk = 0; kk < 9; ++kk) {
        float a = As[(kk * 8 + isub) * 64 + b];
        #pragma unroll
        for (int j = 0; j < 16; ++j)
          acc[j] = fmaf(a, wp[(size_t)j * W_OST + kk], acc[j]);
      }
    }
  }
  size_t ob = ((size_t)b * 64 + o0) * NLOC + loc;
  #pragma unroll
  for (int j = 0; j < 16; ++j) out[ob + (size_t)j * NLOC] = acc[j];
}

// ---------------------------------------------------------------------------
extern "C" void kernel_launch(void* const* d_in, const int* in_sizes, int n_in,
                              void* d_out, int out_size, void* d_ws, size_t ws_size,
                              hipStream_t stream) {
  const float* x  = (const float*)d_in[0];
  const float* wt = (const float*)d_in[1];
  const float* bs = (const float*)d_in[2];
  float* out = (float*)d_out;

  if (ws_size >= WS_NEED) {
    unsigned short* xtb = (unsigned short*)d_ws;
    unsigned short* wt2 = (unsigned short*)((char*)d_ws + XT_BYTES);
    unsigned short* af  = (unsigned short*)((char*)d_ws + XT_BYTES + WT2_BYTES);
    xpose_pad<<<64 * HP_, 256, 0, stream>>>(x, xtb);
    im2col_frag<<<NLOC, 256, 0, stream>>>(xtb, af);
    wtrans<<<4 * 512, 256, 0, stream>>>(wt, wt2);
    lc2d_stream<<<NLOC, 256, 0, stream>>>(af, wt2, bs, out);
  } else {
    lc2d_fallback<<<NLOC, 256, 0, stream>>>(x, wt, bs, out);
  }
}

// Round 5
// 286.926 us; speedup vs baseline: 1.0976x; 1.0976x over previous
//
#include <hip/hip_runtime.h>
#include <hip/hip_bf16.h>

// LocallyConnected2d: y[b,o,h,w] = bias[o,h,w] +
//   sum_{i,kh,kw} xpad[b,i,h+kh,w+kw] * weight[i,o,h,w,kh,kw]
// B=64, CIN=COUT=64, H=W=32, K=3, pad=1, fp32 in/out.
// Per-loc GEMM Y[64b][64o] += X[64b][576k] W[576k][64o] on bf16 MFMA.
// Round 5: FUSED weight path. Block = 4 consecutive-w locs so weight reads
// are dense float4 along (loc,kk); K re-chunked as (4i x 8kk) per 32-chunk
// (kk=8 stashed to LDS, consumed as 2 final i-major chunks) so weight is
// read ONCE, coalesced, transposed in LDS to B-frags, MFMA'd immediately.
// A comes from af (im2col pass) in the SAME k-order.

#define B_    64
#define HW_   32
#define HP_   34
#define NLOC  1024
#define W_OST 9216u     // floats per o step
#define W_IST 589824u   // floats per i step
#define XT_BYTES  ((size_t)64*HP_*HP_*64*2)          //  9,469,952
#define AF_BYTES  ((size_t)NLOC*18*4*64*16)          // 75,497,472
#define WS_NEED   (XT_BYTES + AF_BYTES)              // 84,967,424

typedef __attribute__((ext_vector_type(8))) short short8;
typedef __attribute__((ext_vector_type(8))) unsigned short ushort8;
typedef __attribute__((ext_vector_type(4))) float floatx4;

static __device__ __forceinline__ unsigned short f2bf(float f) {
  __hip_bfloat16 h = __float2bfloat16(f);   // RNE
  return __builtin_bit_cast(unsigned short, h);
}

// ---------------------------------------------------------------------------
// Kernel 1: pad+transpose x[b][i][h][w] (fp32) -> xt[i][hh][ww][b] (bf16).
// (verified rounds 2-4)
// ---------------------------------------------------------------------------
__global__ __launch_bounds__(256) void xpose_pad(const float* __restrict__ x,
                                                 unsigned short* __restrict__ xt) {
  int bid = blockIdx.x;                 // 64*34
  int i = bid / HP_, hh = bid % HP_;
  __shared__ float tile[B_ * 33];
  int t = threadIdx.x;
  bool interior = (hh >= 1 && hh <= HW_);
  if (interior) {
    int h = hh - 1, w = t & 31, bs = t >> 5;
    #pragma unroll
    for (int r = 0; r < 8; ++r) {
      int b = r * 8 + bs;
      tile[b * 33 + w] = x[(((size_t)b * 64 + i) * HW_ + h) * HW_ + w];
    }
  }
  __syncthreads();
  int b = t & 63, wsb = t >> 6;
  size_t base = (size_t)(i * HP_ + hh) * HP_ * B_;
  #pragma unroll
  for (int s = 0; s < 9; ++s) {
    int ww = s * 4 + wsb;
    if (ww < HP_) {
      float v = 0.f;
      if (interior && ww >= 1 && ww <= HW_) v = tile[b * 33 + (ww - 1)];
      xt[base + (size_t)ww * B_ + b] = f2bf(v);
    }
  }
}

// ---------------------------------------------------------------------------
// Kernel 2: im2col in MFMA A-fragment order, NEW k-order:
//   chunk c<16:  within-chunk k' = quad*8+j  <->  i = 4c+quad, kk = j (0..7)
//   chunk 16+sc: k' = quad*8+j <-> i = sc*32+quad*8+j, kk = 8 (kh=kw=2)
// Same verified per-wave 2-step LDS transpose; only the row->(i,kh,kw)
// mapping changes. Producer wave wv == consumer quad.
// ---------------------------------------------------------------------------
__global__ __launch_bounds__(256) void im2col_frag(
    const unsigned short* __restrict__ xt,
    unsigned short* __restrict__ af) {
  __shared__ unsigned short scr[4][512];
  const int bid  = blockIdx.x;
  const int loc  = ((bid & 7) << 7) | (bid >> 3);   // XCD swizzle
  const int hblk = loc >> 5, wblk = loc & 31;
  const int tid  = threadIdx.x;
  const int lane = tid & 63;
  const int wv   = tid >> 6;

  #pragma unroll 1
  for (int c = 0; c < 18; ++c) {
    int i, kh, kw;
    if (c < 16) {
      i = (c << 2) + wv;
      int kk = lane >> 3;              // 0..7
      kh = kk / 3; kw = kk - kh * 3;
    } else {
      i = (c - 16) * 32 + wv * 8 + (lane >> 3);
      kh = 2; kw = 2;
    }
    const ushort8* src = (const ushort8*)(xt +
        (((unsigned)i * HP_ + (unsigned)(hblk + kh)) * HP_ + (unsigned)(wblk + kw)) * 64u
        + ((unsigned)(lane & 7) << 3));
    ushort8 v = *src;
    *(ushort8*)&scr[wv][lane << 3] = v;
    __asm__ volatile("s_waitcnt lgkmcnt(0)" ::: "memory");
    ushort8 p;
    #pragma unroll
    for (int jr = 0; jr < 8; ++jr) p[jr] = scr[wv][jr * 64 + lane];
    __asm__ volatile("s_waitcnt lgkmcnt(0)" ::: "memory");
    size_t slot = ((size_t)(loc * 18 + c) * 4 + (size_t)(lane >> 4)) * 64
                + (size_t)((lane & 15) + (wv << 4));
    *(ushort8*)(af + (slot << 3)) = p;
  }
}

// ---------------------------------------------------------------------------
// Kernel 3: fused weight-transform + GEMM.
// Block = 4 consecutive-w locs, 512 thr = 8 waves: wave = (ll, o-half nh).
// Per chunk c<16: stage weight[i=4c..4c+3][all o][4 locs][kk 0..8] via dense
// float4 (granule = 36 contiguous floats per (i,o)); kk<8 -> Bf[dbuf] in
// B-frag order, kk=8 -> Bs stash. MFMA consumes Bf + af. Chunks 16,17 from Bs.
// ---------------------------------------------------------------------------
__global__ __launch_bounds__(512, 2) void lc2d_fused(
    const unsigned short* __restrict__ af,
    const float* __restrict__ wsrc,
    const float* __restrict__ bias,
    float* __restrict__ out) {
  __shared__ unsigned short Bf[2][4 * 4 * 64 * 8];   // 2 x 16 KB
  __shared__ unsigned short Bs[4 * 2 * 4 * 64 * 8];  // 32 KB stash (kk=8)

  const int bid  = blockIdx.x;                 // 256 blocks
  const int loc0 = bid << 2;
  const int tid  = threadIdx.x;
  const int lane = tid & 63;
  const int wv8  = tid >> 6;
  const int ll   = wv8 >> 1;                   // wave's loc index 0..3
  const int nh   = wv8 & 1;                    // o-half
  const int loc  = loc0 + ll;
  const int col  = lane & 15;
  const int quad = lane >> 4;
  const int o_0  = nh * 32 + col;              // o for nt2=0 (nt2=1 -> +16)

  floatx4 acc[4][2];
  {
    float b0 = bias[(unsigned)o_0 * 1024u + (unsigned)loc];
    float b1 = bias[(unsigned)(o_0 + 16) * 1024u + (unsigned)loc];
    #pragma unroll
    for (int mt = 0; mt < 4; ++mt) {
      acc[mt][0] = (floatx4){b0, b0, b0, b0};
      acc[mt][1] = (floatx4){b1, b1, b1, b1};
    }
  }

  // ---- weight staging: 2304 float4 per chunk (4i x 64o x 36 floats)
  floatx4 wreg[5];
  const bool lastok = (tid < 256);             // round 4 covers idx 2048..2303
  const size_t wrow = (size_t)loc0 * 9;        // 16B-aligned (loc0 % 4 == 0)

  auto issueW = [&](int c) {
    const int i0 = c << 2;
    #pragma unroll
    for (int r = 0; r < 5; ++r) {
      if (r < 4 || lastok) {
        int idx = r * 512 + tid;
        int g = idx / 9, p = idx - g * 9;      // granule, float4-pos
        int i = i0 + (g >> 6), o = g & 63;
        wreg[r] = *(const floatx4*)(wsrc + (size_t)i * W_IST + (size_t)o * W_OST
                                    + wrow + (size_t)(p * 4));
      }
    }
  };
  auto scatterW = [&](int c, int buf) {
    const int i0 = c << 2;
    #pragma unroll
    for (int r = 0; r < 5; ++r) {
      if (r < 4 || lastok) {
        int idx = r * 512 + tid;
        int g = idx / 9, p = idx - g * 9;
        int iq = g >> 6, o = g & 63;
        int ot = o >> 4, oc = o & 15;
        int flane = iq * 16 + oc;              // B-frag lane: quad=iq, col=oc
        #pragma unroll
        for (int e = 0; e < 4; ++e) {
          int fi = p * 4 + e;                  // 0..35 within granule
          int lle = fi / 9, kk = fi - lle * 9;
          unsigned short v = f2bf(wreg[r][e]);
          if (kk < 8) {
            Bf[buf][((lle * 4 + ot) * 64 + flane) * 8 + kk] = v;
          } else {                             // kk == 8 -> stash, k' = i&31
            int i = i0 + iq;
            int sc = i >> 5, k2 = i & 31;
            Bs[((lle * 8 + sc * 4 + ot) * 64 + (k2 >> 3) * 16 + oc) * 8 + (k2 & 7)] = v;
          }
        }
      }
    }
  };

  // ---- A fragments, direct from af (same k-order), depth-1 prefetch
  const size_t abase = (size_t)loc * (18 * 4 * 64 * 8) + ((size_t)lane << 3);
  auto ldA = [&](int c, int tl) {
    return *(const ushort8*)(af + abase + ((size_t)(c * 4 + tl) << 9));
  };

  ushort8 pa0 = ldA(0, 0), pa1 = ldA(0, 1), pa2 = ldA(0, 2), pa3 = ldA(0, 3);

  issueW(0);
  scatterW(0, 0);
  __syncthreads();

  int buf = 0;
  #pragma unroll 1
  for (int c = 0; c < 16; ++c) {
    if (c < 15) issueW(c + 1);
    ushort8 a0 = pa0, a1 = pa1, a2 = pa2, a3 = pa3;
    pa0 = ldA(c + 1, 0); pa1 = ldA(c + 1, 1);
    pa2 = ldA(c + 1, 2); pa3 = ldA(c + 1, 3);
    ushort8 b0 = *(const ushort8*)&Bf[buf][((ll * 4 + nh * 2 + 0) * 64 + lane) * 8];
    ushort8 b1 = *(const ushort8*)&Bf[buf][((ll * 4 + nh * 2 + 1) * 64 + lane) * 8];
    acc[0][0] = __builtin_amdgcn_mfma_f32_16x16x32_bf16(
        __builtin_bit_cast(short8, a0), __builtin_bit_cast(short8, b0), acc[0][0], 0, 0, 0);
    acc[1][0] = __builtin_amdgcn_mfma_f32_16x16x32_bf16(
        __builtin_bit_cast(short8, a1), __builtin_bit_cast(short8, b0), acc[1][0], 0, 0, 0);
    acc[2][0] = __builtin_amdgcn_mfma_f32_16x16x32_bf16(
        __builtin_bit_cast(short8, a2), __builtin_bit_cast(short8, b0), acc[2][0], 0, 0, 0);
    acc[3][0] = __builtin_amdgcn_mfma_f32_16x16x32_bf16(
        __builtin_bit_cast(short8, a3), __builtin_bit_cast(short8, b0), acc[3][0], 0, 0, 0);
    acc[0][1] = __builtin_amdgcn_mfma_f32_16x16x32_bf16(
        __builtin_bit_cast(short8, a0), __builtin_bit_cast(short8, b1), acc[0][1], 0, 0, 0);
    acc[1][1] = __builtin_amdgcn_mfma_f32_16x16x32_bf16(
        __builtin_bit_cast(short8, a1), __builtin_bit_cast(short8, b1), acc[1][1], 0, 0, 0);
    acc[2][1] = __builtin_amdgcn_mfma_f32_16x16x32_bf16(
        __builtin_bit_cast(short8, a2), __builtin_bit_cast(short8, b1), acc[2][1], 0, 0, 0);
    acc[3][1] = __builtin_amdgcn_mfma_f32_16x16x32_bf16(
        __builtin_bit_cast(short8, a3), __builtin_bit_cast(short8, b1), acc[3][1], 0, 0, 0);
    if (c < 15) scatterW(c + 1, buf ^ 1);
    __syncthreads();
    buf ^= 1;
  }

  // ---- stash chunks (kk=8): c = 16, 17
  #pragma unroll
  for (int sc = 0; sc < 2; ++sc) {
    ushort8 a0 = pa0, a1 = pa1, a2 = pa2, a3 = pa3;
    if (sc == 0) { pa0 = ldA(17, 0); pa1 = ldA(17, 1); pa2 = ldA(17, 2); pa3 = ldA(17, 3); }
    ushort8 b0 = *(const ushort8*)&Bs[((ll * 8 + sc * 4 + nh * 2 + 0) * 64 + lane) * 8];
    ushort8 b1 = *(const ushort8*)&Bs[((ll * 8 + sc * 4 + nh * 2 + 1) * 64 + lane) * 8];
    acc[0][0] = __builtin_amdgcn_mfma_f32_16x16x32_bf16(
        __builtin_bit_cast(short8, a0), __builtin_bit_cast(short8, b0), acc[0][0], 0, 0, 0);
    acc[1][0] = __builtin_amdgcn_mfma_f32_16x16x32_bf16(
        __builtin_bit_cast(short8, a1), __builtin_bit_cast(short8, b0), acc[1][0], 0, 0, 0);
    acc[2][0] = __builtin_amdgcn_mfma_f32_16x16x32_bf16(
        __builtin_bit_cast(short8, a2), __builtin_bit_cast(short8, b0), acc[2][0], 0, 0, 0);
    acc[3][0] = __builtin_amdgcn_mfma_f32_16x16x32_bf16(
        __builtin_bit_cast(short8, a3), __builtin_bit_cast(short8, b0), acc[3][0], 0, 0, 0);
    acc[0][1] = __builtin_amdgcn_mfma_f32_16x16x32_bf16(
        __builtin_bit_cast(short8, a0), __builtin_bit_cast(short8, b1), acc[0][1], 0, 0, 0);
    acc[1][1] = __builtin_amdgcn_mfma_f32_16x16x32_bf16(
        __builtin_bit_cast(short8, a1), __builtin_bit_cast(short8, b1), acc[1][1], 0, 0, 0);
    acc[2][1] = __builtin_amdgcn_mfma_f32_16x16x32_bf16(
        __builtin_bit_cast(short8, a2), __builtin_bit_cast(short8, b1), acc[2][1], 0, 0, 0);
    acc[3][1] = __builtin_amdgcn_mfma_f32_16x16x32_bf16(
        __builtin_bit_cast(short8, a3), __builtin_bit_cast(short8, b1), acc[3][1], 0, 0, 0);
  }

  // ---- epilogue: D mapping col=o=lane&15, row=b = mt*16 + quad*4 + r (verified)
  #pragma unroll
  for (int mt = 0; mt < 4; ++mt) {
    int b = mt * 16 + quad * 4;
    #pragma unroll
    for (int r = 0; r < 4; ++r) {
      out[((unsigned)(b + r) * 64u + (unsigned)o_0) * 1024u + (unsigned)loc] = acc[mt][0][r];
      out[((unsigned)(b + r) * 64u + (unsigned)(o_0 + 16)) * 1024u + (unsigned)loc] = acc[mt][1][r];
    }
  }
}

// ---------------------------------------------------------------------------
// Fallback (tiny ws): fp32, direct x reads (round 1, correct for any ws).
// ---------------------------------------------------------------------------
__global__ __launch_bounds__(256, 4) void lc2d_fallback(
    const float* __restrict__ x, const float* __restrict__ weight,
    const float* __restrict__ bias, float* __restrict__ out) {
  int t0 = blockIdx.x;
  int loc = ((t0 & 7) << 7) | (t0 >> 3);
  int h = loc >> 5, w = loc & 31;
  int tid = threadIdx.x;
  int b = tid & 63;
  int o0 = (tid >> 6) * 16;
  __shared__ float As[72 * 64];
  float acc[16];
  #pragma unroll
  for (int j = 0; j < 16; ++j) acc[j] = bias[(size_t)(o0 + j) * NLOC + loc];
  for (int ic = 0; ic < 8; ++ic) {
    __syncthreads();
    #pragma unroll
    for (int s = 0; s < 18; ++s) {
      int f = s * 256 + tid;
      int k = f >> 6, lb = f & 63;
      int kk = k >> 3, isub = k & 7;
      int i = ic * 8 + isub;
      int kh = kk / 3, kw = kk - kh * 3;
      int hh = h + kh - 1, ww = w + kw - 1;
      float v = (hh >= 0 && hh < HW_ && ww >= 0 && ww < HW_)
                  ? x[(((size_t)lb * 64 + i) * HW_ + hh) * HW_ + ww] : 0.f;
      As[k * 64 + lb] = v;
    }
    __syncthreads();
    #pragma unroll 1
    for (int isub = 0; isub < 8; ++isub) {
      const float* wp = weight + (size_t)(ic * 8 + isub) * W_IST
                               + (size_t)o0 * W_OST + loc * 9;
      #pragma unroll
      for (int kk = 0; kk < 9; ++kk) {
        float a = As[(kk * 8 + isub) * 64 + b];
        #pragma unroll
        for (int j = 0; j < 16; ++j)
          acc[j] = fmaf(a, wp[(size_t)j * W_OST + kk], acc[j]);
      }
    }
  }
  size_t ob = ((size_t)b * 64 + o0) * NLOC + loc;
  #pragma unroll
  for (int j = 0; j < 16; ++j) out[ob + (size_t)j * NLOC] = acc[j];
}

// ---------------------------------------------------------------------------
extern "C" void kernel_launch(void* const* d_in, const int* in_sizes, int n_in,
                              void* d_out, int out_size, void* d_ws, size_t ws_size,
                              hipStream_t stream) {
  const float* x  = (const float*)d_in[0];
  const float* wt = (const float*)d_in[1];
  const float* bs = (const float*)d_in[2];
  float* out = (float*)d_out;

  if (ws_size >= WS_NEED) {
    unsigned short* xtb = (unsigned short*)d_ws;
    unsigned short* af  = (unsigned short*)((char*)d_ws + XT_BYTES);
    xpose_pad<<<64 * HP_, 256, 0, stream>>>(x, xtb);
    im2col_frag<<<NLOC, 256, 0, stream>>>(xtb, af);
    lc2d_fused<<<NLOC / 4, 512, 0, stream>>>(af, wt, bs, out);
  } else {
    lc2d_fallback<<<NLOC, 256, 0, stream>>>(x, wt, bs, out);
  }
}